// Round 6
// baseline (253.089 us; speedup 1.0000x reference)
//
#include <hip/hip_runtime.h>

// B=64, S=512, D=768 fp32.
// out = concat( hidden[:,0,:] (64*768), segment-mean by sent_id (64*20*768) )
//
// K1 zero_srep: zero out's sent_reps region (harness poisons it 0xAA).
// K2 aspire_main: grid (64 b, 4 dc, 8 sc) = 2048 blocks x 256 thr (4 waves)
//    = exactly 8 blocks/CU = 32 waves/CU (max occupancy) for streaming BW.
//    Block = (batch, 192-float col chunk, 64-row S chunk). Hot loop per row:
//    dwordx3 load + 3x native ds_add_f32 (unsafeAtomicAdd, fire-and-forget,
//    no waitcnt) into LDS acc[21][192]; sids packed 4/VGPR -> no LDS reads
//    in loop. Epilogue: native global fp32 atomics into zeroed sent_reps.
// K3 aspire_fin: per-batch histogram, divide sent_reps in place.

constexpr int B_  = 64;
constexpr int S_  = 512;
constexpr int D_  = 768;
constexpr int M1  = 21;      // sid in [0,20]
constexpr int MS  = 20;      // segments emitted
constexpr int CF  = 192;     // floats per column chunk (64 lanes x 3)
constexpr int NDC = 4;       // D / CF
constexpr int NSC = 8;       // S chunks
constexpr int SC  = S_ / NSC;   // 64 rows per chunk
constexpr int NT  = 256;     // threads per block = 4 waves
constexpr int RPW = SC / 4;  // 16 rows per wave
constexpr int P   = 8;       // prefetch ring depth

struct f3 { float x, y, z; };

__global__ __launch_bounds__(NT)
void zero_srep(float* __restrict__ out) {
    int i = blockIdx.x * NT + threadIdx.x;   // grid sized exactly
    float4 z = {0.f, 0.f, 0.f, 0.f};
    ((float4*)(out + (size_t)B_ * D_))[i] = z;
}

__global__ __launch_bounds__(NT, 8)
void aspire_main(const float* __restrict__ hidden,
                 const int* __restrict__ sent_ids,
                 float* __restrict__ out) {
    __shared__ float acc[M1 * CF];   // 16128 B
    __shared__ int   sids_c[SC];
    __shared__ int   ccnt[M1];

    const int b    = blockIdx.x;
    const int dc   = blockIdx.y;
    const int sc   = blockIdx.z;
    const int tid  = threadIdx.x;
    const int lane = tid & 63;
    const int w    = tid >> 6;       // 0..3

    for (int i = tid; i < M1 * CF; i += NT) acc[i] = 0.0f;
    if (tid < M1) ccnt[tid] = 0;
    __syncthreads();
    if (tid < SC) {
        int sv = sent_ids[b * S_ + sc * SC + tid];
        sids_c[tid] = sv;
        atomicAdd(&ccnt[sv], 1);     // int LDS atomic (native)
    }
    if (sc == 0 && tid < CF) {       // doc_cls_reps
        out[b * D_ + dc * CF + tid] = hidden[(size_t)b * S_ * D_ + dc * CF + tid];
    }
    __syncthreads();

    // pack this wave's 16 sids into 4 VGPRs (no LDS reads in hot loop)
    const int s0 = w * RPW;
    unsigned pk[4];
    #pragma unroll
    for (int q = 0; q < 4; ++q) {
        pk[q] = (unsigned)sids_c[s0 + 4*q]
              | ((unsigned)sids_c[s0 + 4*q + 1] << 8)
              | ((unsigned)sids_c[s0 + 4*q + 2] << 16)
              | ((unsigned)sids_c[s0 + 4*q + 3] << 24);
    }

    // hot loop: wave w streams rows [s0, s0+16) of this 64-row chunk
    const float* hb = hidden + ((size_t)b * S_ + sc * SC + s0) * D_ + dc * CF + 3 * lane;

    f3 buf[P];
    #pragma unroll
    for (int j = 0; j < P; ++j) buf[j] = *(const f3*)(hb + (size_t)j * D_);

    #pragma unroll
    for (int j = 0; j < RPW; ++j) {
        int sid = (pk[j >> 2] >> ((j & 3) * 8)) & 0xff;   // pure VALU
        float* a = &acc[sid * CF + 3 * lane];
        f3 v = buf[j & (P - 1)];
        unsafeAtomicAdd(a + 0, v.x);     // ds_add_f32: fire-and-forget
        unsafeAtomicAdd(a + 1, v.y);
        unsafeAtomicAdd(a + 2, v.z);
        if (j + P < RPW)
            buf[j & (P - 1)] = *(const f3*)(hb + (size_t)(j + P) * D_);
    }
    __syncthreads();

    // flush partial sums: native global fp32 atomics into zeroed sent_reps
    float* srep = out + (size_t)B_ * D_;
    for (int f = tid; f < MS * CF; f += NT) {
        int seg = f / CF;
        int col = f - seg * CF;
        if (ccnt[seg] != 0) {
            unsafeAtomicAdd(&srep[((size_t)b * MS + seg) * D_ + dc * CF + col],
                            acc[seg * CF + col]);
        }
    }
}

__global__ __launch_bounds__(NT)
void aspire_fin(const int* __restrict__ sent_ids, float* __restrict__ out) {
    __shared__ int cnt[M1];
    const int b   = blockIdx.x;
    const int tid = threadIdx.x;
    if (tid < M1) cnt[tid] = 0;
    __syncthreads();
    for (int i = tid; i < S_; i += NT)
        atomicAdd(&cnt[sent_ids[b * S_ + i]], 1);
    __syncthreads();

    float4* srep = (float4*)(out + (size_t)B_ * D_ + (size_t)b * MS * D_);
    for (int f4 = tid; f4 < MS * D_ / 4; f4 += NT) {
        int seg = (f4 * 4) / D_;
        float ct = (float)cnt[seg];
        ct = ct < 1.0f ? 1.0f : ct;
        float inv = 1.0f / ct;
        float4 v = srep[f4];
        v.x *= inv; v.y *= inv; v.z *= inv; v.w *= inv;
        srep[f4] = v;
    }
}

extern "C" void kernel_launch(void* const* d_in, const int* in_sizes, int n_in,
                              void* d_out, int out_size, void* d_ws, size_t ws_size,
                              hipStream_t stream) {
    const float* hidden   = (const float*)d_in[0];
    const int*   sent_ids = (const int*)d_in[1];
    float* out = (float*)d_out;

    int nz = (B_ * MS * D_ / 4) / NT;          // 960 blocks, exact
    zero_srep<<<nz, NT, 0, stream>>>(out);

    dim3 grid(B_, NDC, NSC);                   // 2048 blocks = 8/CU
    aspire_main<<<grid, NT, 0, stream>>>(hidden, sent_ids, out);

    aspire_fin<<<B_, NT, 0, stream>>>(sent_ids, out);
}

// Round 7
// 164.505 us; speedup vs baseline: 1.5385x; 1.5385x over previous
//
#include <hip/hip_runtime.h>

// B=64, S=512, D=768 fp32.
// out = concat( hidden[:,0,:] (64*768), segment-mean by sent_id (64*20*768) )
//
// K1 zero_srep: zero the sent_reps region (harness poisons out with 0xAA).
// K2 aspire_main: grid (64 b, 4 dc, 2 sc) = 512 blocks x 1024 thr (16 waves)
//    = exactly 2 blocks/CU = 8192 resident waves (chip capacity) -> max
//    streaming BW (~0.75 GB/s/wave model). Block = (batch, 192-float col
//    chunk, 256-row S chunk). Counting-sort chunk rows by sid; each wave owns
//    16 consecutive sorted positions (~2-3 runs). Hot path: dwordx3 load +
//    3 VALU adds, NOTHING else (atomics only inside the rare run-boundary
//    branch -> prefetch ring survives; R1/R2/R6 showed per-row atomics
//    dissolve it). Run flushes: native global_atomic_add_f32 into zeroed
//    sent_reps (seg 20 skipped: it's dropped by the reference).
// K3 aspire_fin: per-batch histogram, divide sent_reps in place.

constexpr int B_  = 64;
constexpr int S_  = 512;
constexpr int D_  = 768;
constexpr int M1  = 21;        // sid in [0,20]
constexpr int MS  = 20;        // segments emitted
constexpr int CF  = 192;       // floats per column chunk (64 lanes x 3)
constexpr int NDC = 4;         // D / CF
constexpr int NSC = 2;         // S chunks
constexpr int SC  = S_ / NSC;  // 256 rows per chunk
constexpr int NT  = 1024;      // threads per block = 16 waves
constexpr int NW  = 16;
constexpr int RPW = SC / NW;   // 16 sorted positions per wave
constexpr int P   = 8;         // prefetch ring depth

struct f3 { float x, y, z; };

__global__ __launch_bounds__(256)
void zero_srep(float* __restrict__ out) {
    int i = blockIdx.x * 256 + threadIdx.x;   // grid sized exactly
    float4 z = {0.f, 0.f, 0.f, 0.f};
    ((float4*)(out + (size_t)B_ * D_))[i] = z;
}

__global__ __launch_bounds__(NT, 8)
void aspire_main(const float* __restrict__ hidden,
                 const int* __restrict__ sent_ids,
                 float* __restrict__ out) {
    __shared__ int   sids_c[SC];
    __shared__ int   ccnt[M1];
    __shared__ int   coffs[M1];
    __shared__ short ord[SC];     // chunk-local row, sorted by sid
    __shared__ short ssid[SC];    // sid at sorted position

    const int b    = blockIdx.x;
    const int dc   = blockIdx.y;
    const int sc   = blockIdx.z;
    const int tid  = threadIdx.x;     // 0..1023
    const int lane = tid & 63;
    const int w    = tid >> 6;        // 0..15

    // ---- counting sort of this 256-row chunk (int LDS atomics only) ----
    if (tid < M1) ccnt[tid] = 0;
    __syncthreads();
    if (tid < SC) {
        int sv = sent_ids[b * S_ + sc * SC + tid];
        sids_c[tid] = sv;
        atomicAdd(&ccnt[sv], 1);      // native ds_add_u32
    }
    if (sc == 0 && tid < CF) {        // doc_cls_reps = hidden[:,0,:]
        out[b * D_ + dc * CF + tid] = hidden[(size_t)b * S_ * D_ + dc * CF + tid];
    }
    __syncthreads();
    if (tid == 0) {
        int r = 0;
        for (int k = 0; k < M1; ++k) { coffs[k] = r; r += ccnt[k]; }
    }
    __syncthreads();
    if (tid < SC) {
        int sv  = sids_c[tid];
        int pos = atomicAdd(&coffs[sv], 1);
        ord[pos]  = (short)tid;
        ssid[pos] = (short)sv;
    }
    __syncthreads();

    // ---- hot loop: registers only; flush at run boundaries ----
    const float* hb = hidden + ((size_t)b * S_ + sc * SC) * D_ + dc * CF + 3 * lane;
    float* srep = out + (size_t)B_ * D_;
    const int p0 = w * RPW;

    f3 buf[P];
    #pragma unroll
    for (int j = 0; j < P; ++j) {
        int s = ord[p0 + j];
        buf[j] = *(const f3*)(hb + (size_t)s * D_);
    }

    float sx = 0.0f, sy = 0.0f, sz = 0.0f;
    int cur = ssid[p0];

    #pragma unroll 1
    for (int t0 = 0; t0 < RPW - P; t0 += P) {
        #pragma unroll
        for (int j = 0; j < P; ++j) {
            int t   = t0 + j;
            int sid = ssid[p0 + t];              // wave-uniform
            if (sid != cur) {                    // rare run boundary
                if (cur != MS) {                 // seg 20 is dropped
                    float* a = &srep[((size_t)b * MS + cur) * D_ + dc * CF + 3 * lane];
                    unsafeAtomicAdd(a + 0, sx);  // global_atomic_add_f32
                    unsafeAtomicAdd(a + 1, sy);
                    unsafeAtomicAdd(a + 2, sz);
                }
                sx = sy = sz = 0.0f;
                cur = sid;
            }
            f3 v = buf[j];
            sx += v.x; sy += v.y; sz += v.z;
            int sn = ord[p0 + t + P];            // refill (independent)
            buf[j] = *(const f3*)(hb + (size_t)sn * D_);
        }
    }
    #pragma unroll
    for (int j = 0; j < P; ++j) {                // tail: consume only
        int t   = RPW - P + j;
        int sid = ssid[p0 + t];
        if (sid != cur) {
            if (cur != MS) {
                float* a = &srep[((size_t)b * MS + cur) * D_ + dc * CF + 3 * lane];
                unsafeAtomicAdd(a + 0, sx);
                unsafeAtomicAdd(a + 1, sy);
                unsafeAtomicAdd(a + 2, sz);
            }
            sx = sy = sz = 0.0f;
            cur = sid;
        }
        f3 v = buf[j];
        sx += v.x; sy += v.y; sz += v.z;
    }
    if (cur != MS) {                             // final flush
        float* a = &srep[((size_t)b * MS + cur) * D_ + dc * CF + 3 * lane];
        unsafeAtomicAdd(a + 0, sx);
        unsafeAtomicAdd(a + 1, sy);
        unsafeAtomicAdd(a + 2, sz);
    }
}

__global__ __launch_bounds__(256)
void aspire_fin(const int* __restrict__ sent_ids, float* __restrict__ out) {
    __shared__ int cnt[M1];
    const int b   = blockIdx.x;
    const int tid = threadIdx.x;
    if (tid < M1) cnt[tid] = 0;
    __syncthreads();
    for (int i = tid; i < S_; i += 256)
        atomicAdd(&cnt[sent_ids[b * S_ + i]], 1);
    __syncthreads();

    float4* srep = (float4*)(out + (size_t)B_ * D_ + (size_t)b * MS * D_);
    for (int f4 = tid; f4 < MS * D_ / 4; f4 += 256) {
        int seg = (f4 * 4) / D_;
        float ct = (float)cnt[seg];
        ct = ct < 1.0f ? 1.0f : ct;
        float inv = 1.0f / ct;
        float4 v = srep[f4];
        v.x *= inv; v.y *= inv; v.z *= inv; v.w *= inv;
        srep[f4] = v;
    }
}

extern "C" void kernel_launch(void* const* d_in, const int* in_sizes, int n_in,
                              void* d_out, int out_size, void* d_ws, size_t ws_size,
                              hipStream_t stream) {
    const float* hidden   = (const float*)d_in[0];
    const int*   sent_ids = (const int*)d_in[1];
    float* out = (float*)d_out;

    int nz = (B_ * MS * D_ / 4) / 256;         // 960 blocks, exact
    zero_srep<<<nz, 256, 0, stream>>>(out);

    dim3 grid(B_, NDC, NSC);                   // (64,4,2) = 512 blocks = 2/CU
    aspire_main<<<grid, NT, 0, stream>>>(hidden, sent_ids, out);

    aspire_fin<<<B_, 256, 0, stream>>>(sent_ids, out);
}